// Round 1
// 422.465 us; speedup vs baseline: 1.0026x; 1.0026x over previous
//
#include <hip/hip_runtime.h>
#include <stdint.h>
#include <stddef.h>

typedef int v4i  __attribute__((ext_vector_type(4)));
typedef int v16i __attribute__((ext_vector_type(16)));

struct QParams {
  float s4, z4, s8, z8, sw, zw;
  float s4sw, s8sw;
  int dw;
};

// ---- float <-> orderable uint encoding for atomic min/max ----
__device__ __forceinline__ unsigned enc_f(float f) {
  unsigned u = __float_as_uint(f);
  return (u & 0x80000000u) ? ~u : (u | 0x80000000u);
}
__device__ __forceinline__ float dec_f(unsigned e) {
  unsigned u = (e & 0x80000000u) ? (e ^ 0x80000000u) : ~e;
  return __uint_as_float(u);
}

// ---------------- init: minmax slots + zero page ----------------
__global__ void k_init(unsigned* mm, unsigned* zp) {
  int t = threadIdx.x;
  if (t < 128) zp[t] = 0u;                 // 512 B zero page
  if (t == 0) { mm[0] = 0xFFFFFFFFu; mm[1] = 0u; mm[2] = 0xFFFFFFFFu; mm[3] = 0u; }
}

// ---------------- global min/max reduction ----------------
__global__ void k_minmax(const float4* __restrict__ p, int n4, unsigned* mm) {
  float lmin = 3.4e38f, lmax = -3.4e38f;
  for (int i = blockIdx.x * blockDim.x + threadIdx.x; i < n4; i += gridDim.x * blockDim.x) {
    float4 v = p[i];
    lmin = fminf(lmin, fminf(fminf(v.x, v.y), fminf(v.z, v.w)));
    lmax = fmaxf(lmax, fmaxf(fmaxf(v.x, v.y), fmaxf(v.z, v.w)));
  }
  for (int off = 32; off; off >>= 1) {
    lmin = fminf(lmin, __shfl_down(lmin, off, 64));
    lmax = fmaxf(lmax, __shfl_down(lmax, off, 64));
  }
  __shared__ float smin[4], smax[4];
  int w = threadIdx.x >> 6, lane = threadIdx.x & 63;
  if (lane == 0) { smin[w] = lmin; smax[w] = lmax; }
  __syncthreads();
  if (threadIdx.x == 0) {
    float a = fminf(fminf(smin[0], smin[1]), fminf(smin[2], smin[3]));
    float b = fmaxf(fmaxf(smax[0], smax[1]), fmaxf(smax[2], smax[3]));
    atomicMin(&mm[0], enc_f(a));
    atomicMax(&mm[1], enc_f(b));
  }
}

// ---------------- quant params (single thread) ----------------
__global__ void k_params(const unsigned* mm, QParams* q) {
  float xmin = dec_f(mm[0]), xmax = dec_f(mm[1]);
  float wmin = dec_f(mm[2]), wmax = dec_f(mm[3]);
  float s4 = (xmax - xmin) / 15.0f + 1e-7f;
  float z4 = truncf(0.0f - xmin / s4);
  float s8 = (xmax - xmin) / 255.0f + 1e-7f;
  float z8 = truncf(0.0f - xmin / s8);
  float sw = (wmax - wmin) / 255.0f + 1e-7f;
  float zw = truncf(0.0f - wmin / sw);
  q->s4 = s4; q->z4 = z4; q->s8 = s8; q->z8 = z8; q->sw = sw; q->zw = zw;
  q->s4sw = s4 * sw; q->s8sw = s8 * sw;
  q->dw = 128 - (int)zw;   // weight offset correction: true tw = (qw-128) + dw
}

// ---------------- weight quant: OIHW fp32 -> Wc[win][kout][c] i8 (qw-128) ----------------
// one block per kout: coalesced stride-256 reads, u32 writes via LDS transpose
__global__ void k_quant_w(const float* __restrict__ w, const QParams* __restrict__ q,
                          char* __restrict__ Wc) {
  __shared__ char sm[2304];
  int b = blockIdx.x;                     // kout
  int tid = threadIdx.x;
  float sw = q->sw, zw = q->zw;
  const float* src = w + (size_t)b * 2304;
#pragma unroll
  for (int j = 0; j < 9; ++j) {
    int o = j * 256 + tid;                // coalesced
    float qf = rintf(__fdiv_rn(src[o], sw) + zw);
    qf = fminf(fmaxf(qf, 0.0f), 255.0f);
    int c = o / 9, jj = o - c * 9;        // OIHW: o = c*9 + jj
    sm[jj * 256 + c] = (char)((int)qf - 128);
  }
  __syncthreads();
  if (tid < 64) {
#pragma unroll
    for (int j = 0; j < 9; ++j)
      *(unsigned*)(Wc + (size_t)j * 65536 + b * 256 + tid * 4) =
          *(const unsigned*)(sm + j * 256 + tid * 4);
  }
}

// ---------------- quantize one float to both 4-bit and 8-bit integer codes ----------------
__device__ __forceinline__ void quant2(float v, float s4, float z4, float s8, float z8,
                                       char& o4, char& o8) {
  float q4 = rintf(__fdiv_rn(v, s4) + z4);
  q4 = fminf(fmaxf(q4, 0.0f), 15.0f);
  o4 = (char)(int)(q4 - z4);                   // exact, in [-15,15]
  float q8 = rintf(__fdiv_rn(v, s8) + z8);
  q8 = fminf(fmaxf(q8, 0.0f), 255.0f);
  int t8 = (int)(q8 - z8);
  o8 = (char)max(-128, min(127, t8));          // 128->127: negligible (LSB path only)
}

// ---------------- x quant + NCHW->NHWC i8 transpose + channel sums ----------------
// grid: 1792 blocks = (n,y); block handles 56 x-positions * 256 channels; float4 reads.
__global__ void k_quant_x(const float4* __restrict__ x4, const QParams* __restrict__ q,
                          char* __restrict__ A4, char* __restrict__ A8,
                          int* __restrict__ CS4, int* __restrict__ CS8) {
  __shared__ char sm4[56 * 260];        // stride 260: u32-aligned, odd word count
  __shared__ char sm8[56 * 260];
  __shared__ int cp4[56][4], cp8[56][4];
  int bx = blockIdx.x;
  int n = bx / 56, y = bx % 56;
  int tid = threadIdx.x;
  float s4 = q->s4, z4 = q->z4, s8 = q->s8, z8 = q->z8;
  const float4* xrow = x4 + (size_t)n * 200704 + y * 14;
#pragma unroll 2
  for (int it = 0; it < 14; ++it) {
    int idx = it * 256 + tid;                 // < 3584
    int c = idx / 14, xq = idx - c * 14;      // float4 group along x
    float4 v = xrow[(size_t)c * 784 + xq];
    int b = (xq * 4) * 260 + c;
    char a0, b0; quant2(v.x, s4, z4, s8, z8, a0, b0);
    char a1, b1; quant2(v.y, s4, z4, s8, z8, a1, b1);
    char a2, b2; quant2(v.z, s4, z4, s8, z8, a2, b2);
    char a3, b3; quant2(v.w, s4, z4, s8, z8, a3, b3);
    sm4[b] = a0; sm4[b + 260] = a1; sm4[b + 520] = a2; sm4[b + 780] = a3;
    sm8[b] = b0; sm8[b + 260] = b1; sm8[b + 520] = b2; sm8[b + 780] = b3;
  }
  __syncthreads();
  if (tid < 224) {                            // channel sums (for dw correction)
    int xc = tid >> 2, qq = tid & 3;
    const unsigned* r4 = (const unsigned*)(sm4 + xc * 260 + qq * 64);
    const unsigned* r8 = (const unsigned*)(sm8 + xc * 260 + qq * 64);
    int a = 0, b = 0;
#pragma unroll
    for (int cw = 0; cw < 16; ++cw) {
      unsigned u = r4[cw], v = r8[cw];
      a += (int)(signed char)(u) + (int)(signed char)(u >> 8)
         + (int)(signed char)(u >> 16) + (int)(signed char)(u >> 24);
      b += (int)(signed char)(v) + (int)(signed char)(v >> 8)
         + (int)(signed char)(v >> 16) + (int)(signed char)(v >> 24);
    }
    cp4[xc][qq] = a; cp8[xc][qq] = b;
  }
  __syncthreads();
  int pixbase = n * 3136 + y * 56;
  if (tid < 56) {
    CS4[pixbase + tid] = cp4[tid][0] + cp4[tid][1] + cp4[tid][2] + cp4[tid][3];
    CS8[pixbase + tid] = cp8[tid][0] + cp8[tid][1] + cp8[tid][2] + cp8[tid][3];
  }
  unsigned* A4w = (unsigned*)A4;
  unsigned* A8w = (unsigned*)A8;
#pragma unroll 2
  for (int it = 0; it < 14; ++it) {
    int idx = it * 256 + tid;                 // < 3584
    int xc = idx >> 6, wd = idx & 63;
    size_t o = (size_t)(pixbase + xc) * 64 + wd;
    A4w[o] = *(const unsigned*)(sm4 + xc * 260 + wd * 4);
    A8w[o] = *(const unsigned*)(sm8 + xc * 260 + wd * 4);
  }
}

// ---------------- 3x3 window sums of channel sums ----------------
__global__ void k_wsum(const int* __restrict__ CS4, const int* __restrict__ CS8,
                       int* __restrict__ S4, int* __restrict__ S8) {
  int p = blockIdx.x * 256 + threadIdx.x;
  if (p >= 100352) return;
  int rem = p % 3136;
  int y = rem / 56, xc = rem % 56;
  int a = 0, b = 0;
#pragma unroll
  for (int dy = -1; dy <= 1; ++dy) {
    if ((unsigned)(y + dy) >= 56u) continue;
#pragma unroll
    for (int dx = -1; dx <= 1; ++dx) {
      if ((unsigned)(xc + dx) >= 56u) continue;
      int qq = p + dy * 56 + dx;
      a += CS4[qq]; b += CS8[qq];
    }
  }
  S4[p] = a; S8[p] = b;
}

// ---------------- fused dual int8 implicit-GEMM conv + epilogue ----------------
#define GLD16(gp, lp)                                                         \
  __builtin_amdgcn_global_load_lds((const __attribute__((address_space(1))) void*)(gp), \
                                   (__attribute__((address_space(3))) void*)(lp), 16, 0, 0)

__device__ __forceinline__ float pg_merge(int a4v, int a8v, float fs4, float fs8) {
  float msb = fs4 * (float)a4v;
  float c8  = fs8 * (float)a8v;
  float lsb = c8 - msb;
  float sig = 1.0f / (1.0f + expf(-msb));
  return msb + (sig > 0.99f ? lsb : 0.0f);
}

struct StagePtrs {
  const char* aBase0; const char* aBase1;
  const char* a8Base0; const char* a8Base1;
  const char* bBase0; const char* bBase1;
  const char* zp0;
  unsigned vm0, vm1;
};

// issue the 6 global_load_lds for K-stage s into the given LDS dests
__device__ __forceinline__ void issue_stage(int s, const StagePtrs& P,
                                            char* dA4, char* dA8, char* dB) {
  int win = s >> 2;
  int cs = (s & 3) << 6;
  int dy = win / 3 - 1;                       // scalar (s is block-uniform)
  int dx = win - (dy + 1) * 3 - 1;
  int doff = (dy * 56 + dx) * 256 + cs;
  bool ok0 = (P.vm0 >> win) & 1;              // bit 9 = 0 -> dummy stage auto-zero for A
  bool ok1 = (P.vm1 >> win) & 1;
  const char* g40 = ok0 ? P.aBase0 + doff : P.zp0;
  const char* g41 = ok1 ? P.aBase1 + doff : P.zp0;
  const char* g80 = ok0 ? P.a8Base0 + doff : P.zp0;
  const char* g81 = ok1 ? P.a8Base1 + doff : P.zp0;
  const char* gB0 = P.bBase0 + win * 65536 + cs;
  const char* gB1 = P.bBase1 + win * 65536 + cs;
  if (s >= 36) { gB0 = P.zp0; gB1 = P.zp0; }  // dummy tail stage: stay in bounds
  GLD16(g40, dA4);       GLD16(g41, dA4 + 1024);
  GLD16(g80, dA8);       GLD16(g81, dA8 + 1024);
  GLD16(gB0, dB);        GLD16(gB1, dB + 1024);
}

__global__ __launch_bounds__(256, 2) void k_conv(
    const char* __restrict__ A4, const char* __restrict__ A8,
    const char* __restrict__ Wc,
    const int* __restrict__ S4, const int* __restrict__ S8,
    const QParams* __restrict__ q, const char* __restrict__ zpage,
    float* __restrict__ out) {
  // 3 buffers: depth-2 prefetch pipeline. 72 KB -> still 2 blocks/CU (144 <= 160 KB).
  __shared__ char smA4[3][8192], smA8[3][8192], smB[3][8192];
  const size_t ASZ = 25690112;
  int tid = threadIdx.x;
  int w = tid >> 6, lane = tid & 63;

  // XCD-chunked swizzle: 1568 blocks (flat), 1568 % 8 == 0 -> bijective chunking.
  // XCD k owns 196 consecutive work items = 98 pixel tiles x both kout halves
  // = exactly 4 images per XCD: all halo/A reuse stays inside one L2.
  int bid = blockIdx.x;
  int swz = (bid & 7) * 196 + (bid >> 3);
  int m0 = (swz >> 1) * 128;         // pixel tile
  int n0 = (swz & 1) * 128;          // kout tile
  int wm = w >> 1, wn = w & 1;       // 2x2 wave grid, wave tile 64x64

  // staging assignment: wave w stages rows [32w,32w+32) of each tile
  int chunk = lane & 3;                         // 16B chunk within 64B row
  int r0 = (w << 5) + (lane >> 2);
  int r1 = r0 + 16;
  int cg0 = chunk ^ ((r0 >> 1) & 3);            // XOR swizzle on global side
  int cg1 = chunk ^ ((r1 >> 1) & 3);
  int p0 = m0 + r0, p1 = m0 + r1;
  int rem0 = p0 % 3136, rem1 = p1 % 3136;
  int y0 = rem0 / 56, x0 = rem0 % 56;
  int y1 = rem1 / 56, x1 = rem1 % 56;

  StagePtrs P;
  P.aBase0 = A4 + (size_t)p0 * 256 + cg0 * 16;
  P.aBase1 = A4 + (size_t)p1 * 256 + cg1 * 16;
  P.a8Base0 = P.aBase0 + ASZ;
  P.a8Base1 = P.aBase1 + ASZ;
  P.bBase0 = Wc + (n0 + r0) * 256 + cg0 * 16;
  P.bBase1 = Wc + (n0 + r1) * 256 + cg1 * 16;
  P.zp0 = zpage + chunk * 16;
  P.vm0 = 0; P.vm1 = 0;
#pragma unroll
  for (int win = 0; win < 9; ++win) {
    int dy = win / 3 - 1, dx = win % 3 - 1;
    P.vm0 |= (unsigned)(((unsigned)(y0 + dy) < 56u) & ((unsigned)(x0 + dx) < 56u)) << win;
    P.vm1 |= (unsigned)(((unsigned)(y1 + dy) < 56u) & ((unsigned)(x1 + dx) < 56u)) << win;
  }

  char* dA4 = &smA4[0][w << 11];
  char* dA8 = &smA8[0][w << 11];
  char* dB  = &smB[0][w << 11];
  const char* smA4f = &smA4[0][0];
  const char* smA8f = &smA8[0][0];
  const char* smBf  = &smB[0][0];

  v16i acc4[2][2] = {}, acc8[2][2] = {};
  int r31 = lane & 31, qh = lane >> 5;

  // precomputed per-lane LDS read offsets (swizzle folded in)
  int offA[2][2], offB[2][2];
#pragma unroll
  for (int fm = 0; fm < 2; ++fm) {
    int row = wm * 64 + fm * 32 + r31;
    int swl = (row >> 1) & 3;
#pragma unroll
    for (int kc = 0; kc < 2; ++kc)
      offA[fm][kc] = row * 64 + (((kc * 2 + qh) ^ swl) << 4);
  }
#pragma unroll
  for (int fn = 0; fn < 2; ++fn) {
    int row = wn * 64 + fn * 32 + r31;
    int swl = (row >> 1) & 3;
#pragma unroll
    for (int kc = 0; kc < 2; ++kc)
      offB[fn][kc] = row * 64 + (((kc * 2 + qh) ^ swl) << 4);
  }

#define COMPUTE(BUF)                                                          \
  {                                                                           \
    _Pragma("unroll")                                                         \
    for (int kc = 0; kc < 2; ++kc) {                                          \
      v4i a4f[2], a8f[2], bf[2];                                              \
      _Pragma("unroll")                                                       \
      for (int fm = 0; fm < 2; ++fm) {                                        \
        a4f[fm] = *(const v4i*)(smA4f + (BUF) * 8192 + offA[fm][kc]);         \
        a8f[fm] = *(const v4i*)(smA8f + (BUF) * 8192 + offA[fm][kc]);         \
      }                                                                       \
      _Pragma("unroll")                                                       \
      for (int fn = 0; fn < 2; ++fn)                                          \
        bf[fn] = *(const v4i*)(smBf + (BUF) * 8192 + offB[fn][kc]);           \
      _Pragma("unroll")                                                       \
      for (int fm = 0; fm < 2; ++fm)                                          \
        _Pragma("unroll")                                                     \
        for (int fn = 0; fn < 2; ++fn) {                                      \
          acc4[fm][fn] = __builtin_amdgcn_mfma_i32_32x32x32_i8(a4f[fm], bf[fn], acc4[fm][fn], 0, 0, 0); \
          acc8[fm][fn] = __builtin_amdgcn_mfma_i32_32x32x32_i8(a8f[fm], bf[fn], acc8[fm][fn], 0, 0, 0); \
        }                                                                     \
    }                                                                         \
  }

  // ---- software pipeline: depth-2 prefetch, 3 buffers, ONE barrier per stage ----
  // Steady state at each phase's wait: vmem queue = [stage s (6), stage s+1 (6)]
  // -> vmcnt(6) completes stage s, leaves s+1 in flight (~2 stage-times of cover).
  // Buffer written by issue(s+2) (= buf[(s+2)%3] = buf[(s-1)%3]) was last read in
  // phase s-1; the barrier at the top of phase s orders all reads before the issue.
  issue_stage(0, P, dA4, dA8, dB);
  issue_stage(1, P, dA4 + 8192, dA8 + 8192, dB + 8192);

#define PHASE(S, RB, WB)                                                      \
  {                                                                           \
    asm volatile("s_waitcnt vmcnt(6)" ::: "memory");                          \
    asm volatile("s_barrier" ::: "memory");                                   \
    issue_stage((S) + 2, P, dA4 + (WB) * 8192, dA8 + (WB) * 8192,             \
                dB + (WB) * 8192);                                            \
    __builtin_amdgcn_s_setprio(1);                                            \
    COMPUTE(RB);                                                              \
    __builtin_amdgcn_s_setprio(0);                                            \
  }

#pragma unroll 1
  for (int sp = 0; sp < 12; ++sp) {
    int s0 = sp * 3;
    PHASE(s0,     0, 2);     // compute buf0, prefetch s0+2 -> buf2
    PHASE(s0 + 1, 1, 0);     // compute buf1, prefetch s0+3 -> buf0
    PHASE(s0 + 2, 2, 1);     // compute buf2, prefetch s0+4 -> buf1
  }
  asm volatile("s_waitcnt vmcnt(0)" ::: "memory");     // retire dummy-stage LDS writes
#undef PHASE
#undef COMPUTE

  // -------- epilogue: exact offset correction, scale, sigmoid gate, NCHW store --------
  float fs4 = q->s4sw, fs8 = q->s8sw;
  int dwv = q->dw;
#pragma unroll
  for (int fm = 0; fm < 2; ++fm)
#pragma unroll
    for (int fn = 0; fn < 2; ++fn) {
      int kout = n0 + wn * 64 + fn * 32 + r31;
      int pb = m0 + wm * 64 + fm * 32 + 4 * qh;
#pragma unroll
      for (int rg = 0; rg < 4; ++rg) {
        int pr = pb + 8 * rg;                   // 4 consecutive pixels, never cross image
        int4 sv4 = *(const int4*)(S4 + pr);
        int4 sv8 = *(const int4*)(S8 + pr);
        float4 res;
        res.x = pg_merge(acc4[fm][fn][rg * 4 + 0] + dwv * sv4.x,
                         acc8[fm][fn][rg * 4 + 0] + dwv * sv8.x, fs4, fs8);
        res.y = pg_merge(acc4[fm][fn][rg * 4 + 1] + dwv * sv4.y,
                         acc8[fm][fn][rg * 4 + 1] + dwv * sv8.y, fs4, fs8);
        res.z = pg_merge(acc4[fm][fn][rg * 4 + 2] + dwv * sv4.z,
                         acc8[fm][fn][rg * 4 + 2] + dwv * sv8.z, fs4, fs8);
        res.w = pg_merge(acc4[fm][fn][rg * 4 + 3] + dwv * sv4.w,
                         acc8[fm][fn][rg * 4 + 3] + dwv * sv8.w, fs4, fs8);
        int nimg = pr / 3136;
        int rem = pr - nimg * 3136;
        *(float4*)(out + (size_t)nimg * 802816 + (size_t)kout * 3136 + rem) = res;
      }
    }
}

// ---------------- launch ----------------
extern "C" void kernel_launch(void* const* d_in, const int* in_sizes, int n_in,
                              void* d_out, int out_size, void* d_ws, size_t ws_size,
                              hipStream_t stream) {
  const float* x  = (const float*)d_in[0];
  const float* wt = (const float*)d_in[1];
  float* out = (float*)d_out;

  char* ws = (char*)d_ws;
  unsigned* mm = (unsigned*)ws;                 // 4 minmax slots
  QParams* prm = (QParams*)(ws + 64);
  char* zpage = ws + 256;                       // 512 B zeros
  char* A4 = ws + 1024;
  const size_t ASZ = 25690112;                  // 32*56*56*256
  char* A8 = A4 + ASZ;
  int* CS4 = (int*)(A8 + ASZ);
  int* CS8 = CS4 + 100352;
  int* S4  = CS8 + 100352;
  int* S8  = S4 + 100352;
  char* Wc = (char*)(S8 + 100352);              // 9*65536 bytes; total ~53.6 MB

  k_init<<<1, 256, 0, stream>>>(mm, (unsigned*)zpage);
  k_minmax<<<1024, 256, 0, stream>>>((const float4*)x, 25690112 / 4, mm);
  k_minmax<<<64, 256, 0, stream>>>((const float4*)wt, 589824 / 4, mm + 2);
  k_params<<<1, 1, 0, stream>>>(mm, prm);
  k_quant_w<<<256, 256, 0, stream>>>(wt, prm, Wc);
  k_quant_x<<<1792, 256, 0, stream>>>((const float4*)x, prm, A4, A8, CS4, CS8);
  k_wsum<<<392, 256, 0, stream>>>(CS4, CS8, S4, S8);
  k_conv<<<dim3(1568), 256, 0, stream>>>(A4, A8, Wc, S4, S8, prm, zpage, out);
}

// Round 2
// 408.414 us; speedup vs baseline: 1.0371x; 1.0344x over previous
//
#include <hip/hip_runtime.h>
#include <stdint.h>
#include <stddef.h>

typedef int v4i  __attribute__((ext_vector_type(4)));
typedef int v16i __attribute__((ext_vector_type(16)));

struct QParams {
  float s4, z4, s8, z8, sw, zw;
  float s4sw, s8sw;
  int dw;
};

// ---- float <-> orderable uint encoding for atomic min/max ----
__device__ __forceinline__ unsigned enc_f(float f) {
  unsigned u = __float_as_uint(f);
  return (u & 0x80000000u) ? ~u : (u | 0x80000000u);
}
__device__ __forceinline__ float dec_f(unsigned e) {
  unsigned u = (e & 0x80000000u) ? (e ^ 0x80000000u) : ~e;
  return __uint_as_float(u);
}

// ---------------- init: minmax slots + zero page ----------------
__global__ void k_init(unsigned* mm, unsigned* zp) {
  int t = threadIdx.x;
  if (t < 128) zp[t] = 0u;                 // 512 B zero page
  if (t == 0) { mm[0] = 0xFFFFFFFFu; mm[1] = 0u; mm[2] = 0xFFFFFFFFu; mm[3] = 0u; }
}

// ---------------- global min/max reduction (x and w in one launch) ----------------
__global__ void k_minmax2(const float4* __restrict__ x, int nx4,
                          const float4* __restrict__ w, int nw4, unsigned* mm) {
  const float4* p; int n4; unsigned* slot; int base; int nblk;
  if (blockIdx.x < 1024) { p = x; n4 = nx4; slot = mm;     base = blockIdx.x;        nblk = 1024; }
  else                   { p = w; n4 = nw4; slot = mm + 2; base = blockIdx.x - 1024; nblk = 64; }
  float lmin = 3.4e38f, lmax = -3.4e38f;
  for (int i = base * blockDim.x + threadIdx.x; i < n4; i += nblk * blockDim.x) {
    float4 v = p[i];
    lmin = fminf(lmin, fminf(fminf(v.x, v.y), fminf(v.z, v.w)));
    lmax = fmaxf(lmax, fmaxf(fmaxf(v.x, v.y), fmaxf(v.z, v.w)));
  }
  for (int off = 32; off; off >>= 1) {
    lmin = fminf(lmin, __shfl_down(lmin, off, 64));
    lmax = fmaxf(lmax, __shfl_down(lmax, off, 64));
  }
  __shared__ float smin[4], smax[4];
  int w2 = threadIdx.x >> 6, lane = threadIdx.x & 63;
  if (lane == 0) { smin[w2] = lmin; smax[w2] = lmax; }
  __syncthreads();
  if (threadIdx.x == 0) {
    float a = fminf(fminf(smin[0], smin[1]), fminf(smin[2], smin[3]));
    float b = fmaxf(fmaxf(smax[0], smax[1]), fmaxf(smax[2], smax[3]));
    atomicMin(&slot[0], enc_f(a));
    atomicMax(&slot[1], enc_f(b));
  }
}

// ---------------- quant params (single thread) ----------------
__global__ void k_params(const unsigned* mm, QParams* q) {
  float xmin = dec_f(mm[0]), xmax = dec_f(mm[1]);
  float wmin = dec_f(mm[2]), wmax = dec_f(mm[3]);
  float s4 = (xmax - xmin) / 15.0f + 1e-7f;
  float z4 = truncf(0.0f - xmin / s4);
  float s8 = (xmax - xmin) / 255.0f + 1e-7f;
  float z8 = truncf(0.0f - xmin / s8);
  float sw = (wmax - wmin) / 255.0f + 1e-7f;
  float zw = truncf(0.0f - wmin / sw);
  q->s4 = s4; q->z4 = z4; q->s8 = s8; q->z8 = z8; q->sw = sw; q->zw = zw;
  q->s4sw = s4 * sw; q->s8sw = s8 * sw;
  q->dw = 128 - (int)zw;   // weight offset correction: true tw = (qw-128) + dw
}

// ---------------- weight quant: OIHW fp32 -> Wc[win][kout][c] i8 (qw-128) ----------------
// one block per kout: coalesced stride-256 reads, u32 writes via LDS transpose
__global__ void k_quant_w(const float* __restrict__ w, const QParams* __restrict__ q,
                          char* __restrict__ Wc) {
  __shared__ char sm[2304];
  int b = blockIdx.x;                     // kout
  int tid = threadIdx.x;
  float sw = q->sw, zw = q->zw;
  const float* src = w + (size_t)b * 2304;
#pragma unroll
  for (int j = 0; j < 9; ++j) {
    int o = j * 256 + tid;                // coalesced
    float qf = rintf(__fdiv_rn(src[o], sw) + zw);
    qf = fminf(fmaxf(qf, 0.0f), 255.0f);
    int c = o / 9, jj = o - c * 9;        // OIHW: o = c*9 + jj
    sm[jj * 256 + c] = (char)((int)qf - 128);
  }
  __syncthreads();
  if (tid < 64) {
#pragma unroll
    for (int j = 0; j < 9; ++j)
      *(unsigned*)(Wc + (size_t)j * 65536 + b * 256 + tid * 4) =
          *(const unsigned*)(sm + j * 256 + tid * 4);
  }
}

// ---------------- quantize one float to both 4-bit and 8-bit integer codes ----------------
__device__ __forceinline__ void quant2(float v, float s4, float z4, float s8, float z8,
                                       char& o4, char& o8) {
  float q4 = rintf(__fdiv_rn(v, s4) + z4);
  q4 = fminf(fmaxf(q4, 0.0f), 15.0f);
  o4 = (char)(int)(q4 - z4);                   // exact, in [-15,15]
  float q8 = rintf(__fdiv_rn(v, s8) + z8);
  q8 = fminf(fmaxf(q8, 0.0f), 255.0f);
  int t8 = (int)(q8 - z8);
  o8 = (char)max(-128, min(127, t8));          // 128->127: negligible (LSB path only)
}

// ---------------- x quant + NCHW->NHWC i8 transpose + channel sums ----------------
// grid: 1792 blocks = (n,y); block handles 56 x-positions * 256 channels; float4 reads.
__global__ void k_quant_x(const float4* __restrict__ x4, const QParams* __restrict__ q,
                          char* __restrict__ A4, char* __restrict__ A8,
                          int* __restrict__ CS4, int* __restrict__ CS8) {
  __shared__ char sm4[56 * 260];        // stride 260: u32-aligned, odd word count
  __shared__ char sm8[56 * 260];
  __shared__ int cp4[56][4], cp8[56][4];
  int bx = blockIdx.x;
  int n = bx / 56, y = bx % 56;
  int tid = threadIdx.x;
  float s4 = q->s4, z4 = q->z4, s8 = q->s8, z8 = q->z8;
  const float4* xrow = x4 + (size_t)n * 200704 + y * 14;
#pragma unroll 2
  for (int it = 0; it < 14; ++it) {
    int idx = it * 256 + tid;                 // < 3584
    int c = idx / 14, xq = idx - c * 14;      // float4 group along x
    float4 v = xrow[(size_t)c * 784 + xq];
    int b = (xq * 4) * 260 + c;
    char a0, b0; quant2(v.x, s4, z4, s8, z8, a0, b0);
    char a1, b1; quant2(v.y, s4, z4, s8, z8, a1, b1);
    char a2, b2; quant2(v.z, s4, z4, s8, z8, a2, b2);
    char a3, b3; quant2(v.w, s4, z4, s8, z8, a3, b3);
    sm4[b] = a0; sm4[b + 260] = a1; sm4[b + 520] = a2; sm4[b + 780] = a3;
    sm8[b] = b0; sm8[b + 260] = b1; sm8[b + 520] = b2; sm8[b + 780] = b3;
  }
  __syncthreads();
  if (tid < 224) {                            // channel sums (for dw correction)
    int xc = tid >> 2, qq = tid & 3;
    const unsigned* r4 = (const unsigned*)(sm4 + xc * 260 + qq * 64);
    const unsigned* r8 = (const unsigned*)(sm8 + xc * 260 + qq * 64);
    int a = 0, b = 0;
#pragma unroll
    for (int cw = 0; cw < 16; ++cw) {
      unsigned u = r4[cw], v = r8[cw];
      a += (int)(signed char)(u) + (int)(signed char)(u >> 8)
         + (int)(signed char)(u >> 16) + (int)(signed char)(u >> 24);
      b += (int)(signed char)(v) + (int)(signed char)(v >> 8)
         + (int)(signed char)(v >> 16) + (int)(signed char)(v >> 24);
    }
    cp4[xc][qq] = a; cp8[xc][qq] = b;
  }
  __syncthreads();
  int pixbase = n * 3136 + y * 56;
  if (tid < 56) {
    CS4[pixbase + tid] = cp4[tid][0] + cp4[tid][1] + cp4[tid][2] + cp4[tid][3];
    CS8[pixbase + tid] = cp8[tid][0] + cp8[tid][1] + cp8[tid][2] + cp8[tid][3];
  }
  unsigned* A4w = (unsigned*)A4;
  unsigned* A8w = (unsigned*)A8;
#pragma unroll 2
  for (int it = 0; it < 14; ++it) {
    int idx = it * 256 + tid;                 // < 3584
    int xc = idx >> 6, wd = idx & 63;
    size_t o = (size_t)(pixbase + xc) * 64 + wd;
    A4w[o] = *(const unsigned*)(sm4 + xc * 260 + wd * 4);
    A8w[o] = *(const unsigned*)(sm8 + xc * 260 + wd * 4);
  }
}

// ---------------- 3x3 window sums of channel sums ----------------
__global__ void k_wsum(const int* __restrict__ CS4, const int* __restrict__ CS8,
                       int* __restrict__ S4, int* __restrict__ S8) {
  int p = blockIdx.x * 256 + threadIdx.x;
  if (p >= 100352) return;
  int rem = p % 3136;
  int y = rem / 56, xc = rem % 56;
  int a = 0, b = 0;
#pragma unroll
  for (int dy = -1; dy <= 1; ++dy) {
    if ((unsigned)(y + dy) >= 56u) continue;
#pragma unroll
    for (int dx = -1; dx <= 1; ++dx) {
      if ((unsigned)(xc + dx) >= 56u) continue;
      int qq = p + dy * 56 + dx;
      a += CS4[qq]; b += CS8[qq];
    }
  }
  S4[p] = a; S8[p] = b;
}

// ---------------- fused dual int8 implicit-GEMM conv + epilogue ----------------
#define GLD16(gp, lp)                                                         \
  __builtin_amdgcn_global_load_lds((const __attribute__((address_space(1))) void*)(gp), \
                                   (__attribute__((address_space(3))) void*)(lp), 16, 0, 0)

__device__ __forceinline__ float pg_merge(int a4v, int a8v, float fs4, float fs8) {
  float msb = fs4 * (float)a4v;
  float c8  = fs8 * (float)a8v;
  float lsb = c8 - msb;
  float sig = 1.0f / (1.0f + expf(-msb));
  return msb + (sig > 0.99f ? lsb : 0.0f);
}

struct StagePtrs {
  const char* aBase0; const char* aBase1;
  const char* a8Base0; const char* a8Base1;
  const char* bBase0; const char* bBase1;
  const char* zp0;
  unsigned vm0, vm1;
};

// half 0: A4 pair + B chunk0; half 1: A8 pair + B chunk1 (3 glds each)
__device__ __forceinline__ void issue_half(int s, int half, const StagePtrs& P,
                                           char* dA4, char* dA8, char* dB) {
  int win = s >> 2;
  int cs = (s & 3) << 6;
  int dy = win / 3 - 1;                       // scalar (s is block-uniform)
  int dx = win - (dy + 1) * 3 - 1;
  int doff = (dy * 56 + dx) * 256 + cs;
  bool ok0 = (P.vm0 >> win) & 1;              // bit 9 = 0 -> dummy stage auto-zero for A
  bool ok1 = (P.vm1 >> win) & 1;
  if (half == 0) {
    const char* g40 = ok0 ? P.aBase0 + doff : P.zp0;
    const char* g41 = ok1 ? P.aBase1 + doff : P.zp0;
    const char* gB0 = P.bBase0 + win * 65536 + cs;
    if (s >= 36) gB0 = P.zp0;                 // dummy tail stage: stay in bounds
    GLD16(g40, dA4); GLD16(g41, dA4 + 1024); GLD16(gB0, dB);
  } else {
    const char* g80 = ok0 ? P.a8Base0 + doff : P.zp0;
    const char* g81 = ok1 ? P.a8Base1 + doff : P.zp0;
    const char* gB1 = P.bBase1 + win * 65536 + cs;
    if (s >= 36) gB1 = P.zp0;
    GLD16(g80, dA8); GLD16(g81, dA8 + 1024); GLD16(gB1, dB + 1024);
  }
}

__global__ __launch_bounds__(256, 2) void k_conv(
    const char* __restrict__ A4, const char* __restrict__ A8,
    const char* __restrict__ Wc,
    const int* __restrict__ S4, const int* __restrict__ S8,
    const QParams* __restrict__ q, const char* __restrict__ zpage,
    float* __restrict__ out) {
  // 3 buffers: depth-2 prefetch pipeline. 72 KB -> 2 blocks/CU (144 <= 160 KB).
  __shared__ char smA4[3][8192], smA8[3][8192], smB[3][8192];
  const size_t ASZ = 25690112;
  int tid = threadIdx.x;
  int w = tid >> 6, lane = tid & 63;

  // XCD-chunked swizzle: 1568 blocks, %8==0 -> bijective chunking.
  // XCD k owns 196 consecutive work items = 98 pixel tiles x both kout halves
  // = exactly 4 images per XCD: all halo/A reuse stays inside one L2.
  int bid = blockIdx.x;
  int swz = (bid & 7) * 196 + (bid >> 3);
  int m0 = (swz >> 1) * 128;         // pixel tile
  int n0 = (swz & 1) * 128;          // kout tile
  int wm = w >> 1, wn = w & 1;       // 2x2 wave grid, wave tile 64x64

  // staging assignment: wave w stages rows [32w,32w+32) of each tile
  int chunk = lane & 3;                         // 16B chunk within 64B row
  int r0 = (w << 5) + (lane >> 2);
  int r1 = r0 + 16;
  int cg0 = chunk ^ ((r0 >> 1) & 3);            // XOR swizzle on global side
  int cg1 = chunk ^ ((r1 >> 1) & 3);
  int p0 = m0 + r0, p1 = m0 + r1;
  int rem0 = p0 % 3136, rem1 = p1 % 3136;
  int y0 = rem0 / 56, x0 = rem0 % 56;
  int y1 = rem1 / 56, x1 = rem1 % 56;

  StagePtrs P;
  P.aBase0 = A4 + (size_t)p0 * 256 + cg0 * 16;
  P.aBase1 = A4 + (size_t)p1 * 256 + cg1 * 16;
  P.a8Base0 = P.aBase0 + ASZ;
  P.a8Base1 = P.aBase1 + ASZ;
  P.bBase0 = Wc + (n0 + r0) * 256 + cg0 * 16;
  P.bBase1 = Wc + (n0 + r1) * 256 + cg1 * 16;
  P.zp0 = zpage + chunk * 16;
  P.vm0 = 0; P.vm1 = 0;
#pragma unroll
  for (int win = 0; win < 9; ++win) {
    int dy = win / 3 - 1, dx = win % 3 - 1;
    P.vm0 |= (unsigned)(((unsigned)(y0 + dy) < 56u) & ((unsigned)(x0 + dx) < 56u)) << win;
    P.vm1 |= (unsigned)(((unsigned)(y1 + dy) < 56u) & ((unsigned)(x1 + dx) < 56u)) << win;
  }

  char* dA4 = &smA4[0][w << 11];
  char* dA8 = &smA8[0][w << 11];
  char* dB  = &smB[0][w << 11];
  const char* smA4f = &smA4[0][0];
  const char* smA8f = &smA8[0][0];
  const char* smBf  = &smB[0][0];

  v16i acc4[2][2] = {}, acc8[2][2] = {};
  int r31 = lane & 31, qh = lane >> 5;

  // precomputed per-lane LDS read offsets (swizzle folded in)
  int offA[2][2], offB[2][2];
#pragma unroll
  for (int fm = 0; fm < 2; ++fm) {
    int row = wm * 64 + fm * 32 + r31;
    int swl = (row >> 1) & 3;
#pragma unroll
    for (int kc = 0; kc < 2; ++kc)
      offA[fm][kc] = row * 64 + (((kc * 2 + qh) ^ swl) << 4);
  }
#pragma unroll
  for (int fn = 0; fn < 2; ++fn) {
    int row = wn * 64 + fn * 32 + r31;
    int swl = (row >> 1) & 3;
#pragma unroll
    for (int kc = 0; kc < 2; ++kc)
      offB[fn][kc] = row * 64 + (((kc * 2 + qh) ^ swl) << 4);
  }

  // ---- sub-phased schedule (T3+T4+T5): per K-stage, two sub-phases.
  // Each sub-phase: {6 ds_read_b128 for this kc  ||  issue half the stage-(s+2)
  // glds} -> s_barrier -> lgkmcnt(0) -> setprio(1) -> 8 MFMA -> setprio(0).
  // One wave's LDS-read burst overlaps other waves' MFMA clusters; the counted
  // vmcnt(6) at stage top keeps 6 glds (one full stage) in flight across phases.
#define SUBPHASE(S, RB, WB, KC)                                               \
  {                                                                           \
    v4i a4f[2], a8f[2], bf[2];                                                \
    _Pragma("unroll")                                                         \
    for (int fm = 0; fm < 2; ++fm) {                                          \
      a4f[fm] = *(const v4i*)(smA4f + (RB) * 8192 + offA[fm][KC]);            \
      a8f[fm] = *(const v4i*)(smA8f + (RB) * 8192 + offA[fm][KC]);            \
    }                                                                         \
    _Pragma("unroll")                                                         \
    for (int fn = 0; fn < 2; ++fn)                                            \
      bf[fn] = *(const v4i*)(smBf + (RB) * 8192 + offB[fn][KC]);              \
    issue_half((S) + 2, KC, P, dA4 + (WB) * 8192, dA8 + (WB) * 8192,          \
               dB + (WB) * 8192);                                             \
    asm volatile("s_barrier" ::: "memory");                                   \
    asm volatile("s_waitcnt lgkmcnt(0)" ::: "memory");                        \
    __builtin_amdgcn_s_setprio(1);                                            \
    _Pragma("unroll")                                                         \
    for (int fm = 0; fm < 2; ++fm)                                            \
      _Pragma("unroll")                                                       \
      for (int fn = 0; fn < 2; ++fn) {                                        \
        acc4[fm][fn] = __builtin_amdgcn_mfma_i32_32x32x32_i8(a4f[fm], bf[fn], acc4[fm][fn], 0, 0, 0); \
        acc8[fm][fn] = __builtin_amdgcn_mfma_i32_32x32x32_i8(a8f[fm], bf[fn], acc8[fm][fn], 0, 0, 0); \
      }                                                                       \
    __builtin_amdgcn_s_setprio(0);                                            \
  }

  // Stage top: retire stage S's 6 glds (oldest; S+1's 6 stay in flight), then
  // barrier so every wave's writes to RB are visible before any wave reads it.
#define PHASE(S, RB, WB)                                                      \
  {                                                                           \
    asm volatile("s_waitcnt vmcnt(6)" ::: "memory");                          \
    asm volatile("s_barrier" ::: "memory");                                   \
    SUBPHASE(S, RB, WB, 0)                                                    \
    SUBPHASE(S, RB, WB, 1)                                                    \
  }

  // prologue: stages 0 and 1 fully in flight (12 outstanding at first PHASE)
  issue_half(0, 0, P, dA4, dA8, dB);
  issue_half(0, 1, P, dA4, dA8, dB);
  issue_half(1, 0, P, dA4 + 8192, dA8 + 8192, dB + 8192);
  issue_half(1, 1, P, dA4 + 8192, dA8 + 8192, dB + 8192);

#pragma unroll 1
  for (int sp = 0; sp < 12; ++sp) {
    int s0 = sp * 3;
    PHASE(s0,     0, 2);     // compute buf0, prefetch s0+2 -> buf2
    PHASE(s0 + 1, 1, 0);     // compute buf1, prefetch s0+3 -> buf0
    PHASE(s0 + 2, 2, 1);     // compute buf2, prefetch s0+4 -> buf1
  }
  asm volatile("s_waitcnt vmcnt(0)" ::: "memory");     // retire dummy-stage LDS writes
#undef PHASE
#undef SUBPHASE

  // -------- epilogue: exact offset correction, scale, sigmoid gate, NCHW store --------
  float fs4 = q->s4sw, fs8 = q->s8sw;
  int dwv = q->dw;
#pragma unroll
  for (int fm = 0; fm < 2; ++fm)
#pragma unroll
    for (int fn = 0; fn < 2; ++fn) {
      int kout = n0 + wn * 64 + fn * 32 + r31;
      int pb = m0 + wm * 64 + fm * 32 + 4 * qh;
#pragma unroll
      for (int rg = 0; rg < 4; ++rg) {
        int pr = pb + 8 * rg;                   // 4 consecutive pixels, never cross image
        int4 sv4 = *(const int4*)(S4 + pr);
        int4 sv8 = *(const int4*)(S8 + pr);
        float4 res;
        res.x = pg_merge(acc4[fm][fn][rg * 4 + 0] + dwv * sv4.x,
                         acc8[fm][fn][rg * 4 + 0] + dwv * sv8.x, fs4, fs8);
        res.y = pg_merge(acc4[fm][fn][rg * 4 + 1] + dwv * sv4.y,
                         acc8[fm][fn][rg * 4 + 1] + dwv * sv8.y, fs4, fs8);
        res.z = pg_merge(acc4[fm][fn][rg * 4 + 2] + dwv * sv4.z,
                         acc8[fm][fn][rg * 4 + 2] + dwv * sv8.z, fs4, fs8);
        res.w = pg_merge(acc4[fm][fn][rg * 4 + 3] + dwv * sv4.w,
                         acc8[fm][fn][rg * 4 + 3] + dwv * sv8.w, fs4, fs8);
        int nimg = pr / 3136;
        int rem = pr - nimg * 3136;
        *(float4*)(out + (size_t)nimg * 802816 + (size_t)kout * 3136 + rem) = res;
      }
    }
}

// ---------------- launch ----------------
extern "C" void kernel_launch(void* const* d_in, const int* in_sizes, int n_in,
                              void* d_out, int out_size, void* d_ws, size_t ws_size,
                              hipStream_t stream) {
  const float* x  = (const float*)d_in[0];
  const float* wt = (const float*)d_in[1];
  float* out = (float*)d_out;

  char* ws = (char*)d_ws;
  unsigned* mm = (unsigned*)ws;                 // 4 minmax slots
  QParams* prm = (QParams*)(ws + 64);
  char* zpage = ws + 256;                       // 512 B zeros
  char* A4 = ws + 1024;
  const size_t ASZ = 25690112;                  // 32*56*56*256
  char* A8 = A4 + ASZ;
  int* CS4 = (int*)(A8 + ASZ);
  int* CS8 = CS4 + 100352;
  int* S4  = CS8 + 100352;
  int* S8  = S4 + 100352;
  char* Wc = (char*)(S8 + 100352);              // 9*65536 bytes; total ~53.6 MB

  k_init<<<1, 256, 0, stream>>>(mm, (unsigned*)zpage);
  k_minmax2<<<1088, 256, 0, stream>>>((const float4*)x, 25690112 / 4,
                                      (const float4*)wt, 589824 / 4, mm);
  k_params<<<1, 1, 0, stream>>>(mm, prm);
  k_quant_w<<<256, 256, 0, stream>>>(wt, prm, Wc);
  k_quant_x<<<1792, 256, 0, stream>>>((const float4*)x, prm, A4, A8, CS4, CS8);
  k_wsum<<<392, 256, 0, stream>>>(CS4, CS8, S4, S8);
  k_conv<<<dim3(1568), 256, 0, stream>>>(A4, A8, Wc, S4, S8, prm, zpage, out);
}

// Round 3
// 374.315 us; speedup vs baseline: 1.1316x; 1.0911x over previous
//
#include <hip/hip_runtime.h>
#include <stdint.h>
#include <stddef.h>

typedef int v4i  __attribute__((ext_vector_type(4)));
typedef int v16i __attribute__((ext_vector_type(16)));

struct QParams {
  float s4, z4, s8, z8, sw, zw;
  float s4sw, s8sw;
  int dw;
};

// ---------------- block-local min/max (atomic-free, no init kernel) ----------------
// blocks 0..1023: x tensor -> mmX[b]; blocks 1024..1087: w tensor -> mmW[b-1024]
__global__ void k_minmax2(const float4* __restrict__ x, int nx4,
                          const float4* __restrict__ w, int nw4,
                          float2* __restrict__ mmX, float2* __restrict__ mmW) {
  const float4* p; int n4; float2* slot; int base; int nblk;
  if (blockIdx.x < 1024) { p = x; n4 = nx4; slot = mmX + blockIdx.x;          base = blockIdx.x;        nblk = 1024; }
  else                   { p = w; n4 = nw4; slot = mmW + (blockIdx.x - 1024); base = blockIdx.x - 1024; nblk = 64; }
  float lmin = 3.4e38f, lmax = -3.4e38f;
  for (int i = base * blockDim.x + threadIdx.x; i < n4; i += nblk * blockDim.x) {
    float4 v = p[i];
    lmin = fminf(lmin, fminf(fminf(v.x, v.y), fminf(v.z, v.w)));
    lmax = fmaxf(lmax, fmaxf(fmaxf(v.x, v.y), fmaxf(v.z, v.w)));
  }
  for (int off = 32; off; off >>= 1) {
    lmin = fminf(lmin, __shfl_down(lmin, off, 64));
    lmax = fmaxf(lmax, __shfl_down(lmax, off, 64));
  }
  __shared__ float smin[4], smax[4];
  int w2 = threadIdx.x >> 6, lane = threadIdx.x & 63;
  if (lane == 0) { smin[w2] = lmin; smax[w2] = lmax; }
  __syncthreads();
  if (threadIdx.x == 0) {
    float2 r;
    r.x = fminf(fminf(smin[0], smin[1]), fminf(smin[2], smin[3]));
    r.y = fmaxf(fmaxf(smax[0], smax[1]), fmaxf(smax[2], smax[3]));
    *slot = r;
  }
}

// ---------------- quantize one float to both 4-bit and 8-bit integer codes ----------------
__device__ __forceinline__ void quant2(float v, float s4, float z4, float s8, float z8,
                                       char& o4, char& o8) {
  float q4 = rintf(__fdiv_rn(v, s4) + z4);
  q4 = fminf(fmaxf(q4, 0.0f), 15.0f);
  o4 = (char)(int)(q4 - z4);                   // exact, in [-15,15]
  float q8 = rintf(__fdiv_rn(v, s8) + z8);
  q8 = fminf(fmaxf(q8, 0.0f), 255.0f);
  int t8 = (int)(q8 - z8);
  o8 = (char)max(-128, min(127, t8));          // 128->127: negligible (LSB path only)
}

// ---------------- fused: params-reduce + {x-quant | w-quant} ----------------
// grid 2048: blocks 0..1791 = quant_x (n,y); blocks 1792..2047 = quant_w (kout).
// Every block re-reduces the 1024+64 minmax partials (deterministic, L2-hot,
// bit-identical across blocks) -> no k_params launch, no cross-kernel wait.
// Block 1792 also publishes QParams + zero page for k_conv.
__global__ void k_quant(const float4* __restrict__ x4, const float* __restrict__ wt,
                        const float2* __restrict__ mmX, const float2* __restrict__ mmW,
                        char* __restrict__ A4, char* __restrict__ A8,
                        int* __restrict__ CS4, int* __restrict__ CS8,
                        char* __restrict__ Wc,
                        QParams* __restrict__ prm, unsigned* __restrict__ zp) {
  __shared__ char sm4[56 * 260];        // stride 260: u32-aligned, odd word count
  __shared__ char sm8[56 * 260];
  __shared__ int cp4[56][4], cp8[56][4];
  __shared__ float s_red[4][4];
  __shared__ QParams sq;
  int tid = threadIdx.x;

  // ---- param reduction (all blocks, ~4 float2 loads/thread) ----
  {
    float xmn = 3.4e38f, xmx = -3.4e38f, wmn = 3.4e38f, wmx = -3.4e38f;
#pragma unroll
    for (int i = 0; i < 4; ++i) {
      float2 v = mmX[i * 256 + tid];
      xmn = fminf(xmn, v.x); xmx = fmaxf(xmx, v.y);
    }
    if (tid < 64) { float2 v = mmW[tid]; wmn = v.x; wmx = v.y; }
    for (int off = 32; off; off >>= 1) {
      xmn = fminf(xmn, __shfl_down(xmn, off, 64));
      xmx = fmaxf(xmx, __shfl_down(xmx, off, 64));
      wmn = fminf(wmn, __shfl_down(wmn, off, 64));
      wmx = fmaxf(wmx, __shfl_down(wmx, off, 64));
    }
    int wv = tid >> 6, ln = tid & 63;
    if (ln == 0) { s_red[wv][0] = xmn; s_red[wv][1] = xmx; s_red[wv][2] = wmn; s_red[wv][3] = wmx; }
    __syncthreads();
    if (tid == 0) {
      float xmin = fminf(fminf(s_red[0][0], s_red[1][0]), fminf(s_red[2][0], s_red[3][0]));
      float xmax = fmaxf(fmaxf(s_red[0][1], s_red[1][1]), fmaxf(s_red[2][1], s_red[3][1]));
      float wmin = fminf(fminf(s_red[0][2], s_red[1][2]), fminf(s_red[2][2], s_red[3][2]));
      float wmax = fmaxf(fmaxf(s_red[0][3], s_red[1][3]), fmaxf(s_red[2][3], s_red[3][3]));
      float s4 = (xmax - xmin) / 15.0f + 1e-7f;
      sq.s4 = s4; sq.z4 = truncf(0.0f - xmin / s4);
      float s8 = (xmax - xmin) / 255.0f + 1e-7f;
      sq.s8 = s8; sq.z8 = truncf(0.0f - xmin / s8);
      float sw = (wmax - wmin) / 255.0f + 1e-7f;
      sq.sw = sw; sq.zw = truncf(0.0f - wmin / sw);
      sq.s4sw = s4 * sw; sq.s8sw = s8 * sw;
      sq.dw = 128 - (int)sq.zw;
    }
    __syncthreads();
  }

  if (blockIdx.x >= 1792) {
    // ---- quant_w: OIHW fp32 -> Wc[win][kout][c] i8 (qw-128) ----
    int b = blockIdx.x - 1792;            // kout
    float sw = sq.sw, zw = sq.zw;
    char* smw = sm4;                      // alias first 2304 B
    const float* src = wt + (size_t)b * 2304;
#pragma unroll
    for (int j = 0; j < 9; ++j) {
      int o = j * 256 + tid;              // coalesced
      float qf = rintf(__fdiv_rn(src[o], sw) + zw);
      qf = fminf(fmaxf(qf, 0.0f), 255.0f);
      int c = o / 9, jj = o - c * 9;      // OIHW: o = c*9 + jj
      smw[jj * 256 + c] = (char)((int)qf - 128);
    }
    __syncthreads();
    if (tid < 64) {
#pragma unroll
      for (int j = 0; j < 9; ++j)
        *(unsigned*)(Wc + (size_t)j * 65536 + b * 256 + tid * 4) =
            *(const unsigned*)(smw + j * 256 + tid * 4);
    }
    if (blockIdx.x == 1792) {             // publish params + zero page for k_conv
      if (tid < 128) zp[tid] = 0u;
      if (tid == 0) *prm = sq;
    }
    return;
  }

  // ---- quant_x: NCHW->NHWC i8 transpose + channel sums ----
  int bx = blockIdx.x;
  int n = bx / 56, y = bx % 56;
  float s4 = sq.s4, z4 = sq.z4, s8 = sq.s8, z8 = sq.z8;
  const float4* xrow = x4 + (size_t)n * 200704 + y * 14;
#pragma unroll 2
  for (int it = 0; it < 14; ++it) {
    int idx = it * 256 + tid;                 // < 3584
    int c = idx / 14, xq = idx - c * 14;      // float4 group along x
    float4 v = xrow[(size_t)c * 784 + xq];
    int b = (xq * 4) * 260 + c;
    char a0, b0; quant2(v.x, s4, z4, s8, z8, a0, b0);
    char a1, b1; quant2(v.y, s4, z4, s8, z8, a1, b1);
    char a2, b2; quant2(v.z, s4, z4, s8, z8, a2, b2);
    char a3, b3; quant2(v.w, s4, z4, s8, z8, a3, b3);
    sm4[b] = a0; sm4[b + 260] = a1; sm4[b + 520] = a2; sm4[b + 780] = a3;
    sm8[b] = b0; sm8[b + 260] = b1; sm8[b + 520] = b2; sm8[b + 780] = b3;
  }
  __syncthreads();
  if (tid < 224) {                            // channel sums (for dw correction)
    int xc = tid >> 2, qq = tid & 3;
    const unsigned* r4 = (const unsigned*)(sm4 + xc * 260 + qq * 64);
    const unsigned* r8 = (const unsigned*)(sm8 + xc * 260 + qq * 64);
    int a = 0, b = 0;
#pragma unroll
    for (int cw = 0; cw < 16; ++cw) {
      unsigned u = r4[cw], v = r8[cw];
      a += (int)(signed char)(u) + (int)(signed char)(u >> 8)
         + (int)(signed char)(u >> 16) + (int)(signed char)(u >> 24);
      b += (int)(signed char)(v) + (int)(signed char)(v >> 8)
         + (int)(signed char)(v >> 16) + (int)(signed char)(v >> 24);
    }
    cp4[xc][qq] = a; cp8[xc][qq] = b;
  }
  __syncthreads();
  int pixbase = n * 3136 + y * 56;
  if (tid < 56) {
    CS4[pixbase + tid] = cp4[tid][0] + cp4[tid][1] + cp4[tid][2] + cp4[tid][3];
    CS8[pixbase + tid] = cp8[tid][0] + cp8[tid][1] + cp8[tid][2] + cp8[tid][3];
  }
  unsigned* A4w = (unsigned*)A4;
  unsigned* A8w = (unsigned*)A8;
#pragma unroll 2
  for (int it = 0; it < 14; ++it) {
    int idx = it * 256 + tid;                 // < 3584
    int xc = idx >> 6, wd = idx & 63;
    size_t o = (size_t)(pixbase + xc) * 64 + wd;
    A4w[o] = *(const unsigned*)(sm4 + xc * 260 + wd * 4);
    A8w[o] = *(const unsigned*)(sm8 + xc * 260 + wd * 4);
  }
}

// ---------------- 3x3 window sums of channel sums ----------------
__global__ void k_wsum(const int* __restrict__ CS4, const int* __restrict__ CS8,
                       int* __restrict__ S4, int* __restrict__ S8) {
  int p = blockIdx.x * 256 + threadIdx.x;
  if (p >= 100352) return;
  int rem = p % 3136;
  int y = rem / 56, xc = rem % 56;
  int a = 0, b = 0;
#pragma unroll
  for (int dy = -1; dy <= 1; ++dy) {
    if ((unsigned)(y + dy) >= 56u) continue;
#pragma unroll
    for (int dx = -1; dx <= 1; ++dx) {
      if ((unsigned)(xc + dx) >= 56u) continue;
      int qq = p + dy * 56 + dx;
      a += CS4[qq]; b += CS8[qq];
    }
  }
  S4[p] = a; S8[p] = b;
}

// ---------------- fused dual int8 implicit-GEMM conv + epilogue ----------------
#define GLD16(gp, lp)                                                         \
  __builtin_amdgcn_global_load_lds((const __attribute__((address_space(1))) void*)(gp), \
                                   (__attribute__((address_space(3))) void*)(lp), 16, 0, 0)

__device__ __forceinline__ float pg_merge(int a4v, int a8v, float fs4, float fs8) {
  float msb = fs4 * (float)a4v;
  float c8  = fs8 * (float)a8v;
  float lsb = c8 - msb;
  float sig = 1.0f / (1.0f + expf(-msb));
  return msb + (sig > 0.99f ? lsb : 0.0f);
}

struct StagePtrs {
  const char* aBase0; const char* aBase1;
  const char* a8Base0; const char* a8Base1;
  const char* bBase0; const char* bBase1;
  const char* zp0;
  unsigned vm0, vm1;
};

// half 0: A4 pair + B chunk0; half 1: A8 pair + B chunk1 (3 glds each)
__device__ __forceinline__ void issue_half(int s, int half, const StagePtrs& P,
                                           char* dA4, char* dA8, char* dB) {
  int win = s >> 2;
  int cs = (s & 3) << 6;
  int dy = win / 3 - 1;                       // scalar (s is block-uniform)
  int dx = win - (dy + 1) * 3 - 1;
  int doff = (dy * 56 + dx) * 256 + cs;
  bool ok0 = (P.vm0 >> win) & 1;              // bit 9 = 0 -> dummy stage auto-zero for A
  bool ok1 = (P.vm1 >> win) & 1;
  if (half == 0) {
    const char* g40 = ok0 ? P.aBase0 + doff : P.zp0;
    const char* g41 = ok1 ? P.aBase1 + doff : P.zp0;
    const char* gB0 = P.bBase0 + win * 65536 + cs;
    if (s >= 36) gB0 = P.zp0;                 // dummy tail stage: stay in bounds
    GLD16(g40, dA4); GLD16(g41, dA4 + 1024); GLD16(gB0, dB);
  } else {
    const char* g80 = ok0 ? P.a8Base0 + doff : P.zp0;
    const char* g81 = ok1 ? P.a8Base1 + doff : P.zp0;
    const char* gB1 = P.bBase1 + win * 65536 + cs;
    if (s >= 36) gB1 = P.zp0;
    GLD16(g80, dA8); GLD16(g81, dA8 + 1024); GLD16(gB1, dB + 1024);
  }
}

__global__ __launch_bounds__(256, 2) void k_conv(
    const char* __restrict__ A4, const char* __restrict__ A8,
    const char* __restrict__ Wc,
    const int* __restrict__ S4, const int* __restrict__ S8,
    const QParams* __restrict__ q, const char* __restrict__ zpage,
    float* __restrict__ out) {
  // 3 buffers: depth-2 prefetch pipeline. 72 KB -> 2 blocks/CU (144 <= 160 KB).
  __shared__ char smA4[3][8192], smA8[3][8192], smB[3][8192];
  const size_t ASZ = 25690112;
  int tid = threadIdx.x;
  int w = tid >> 6, lane = tid & 63;

  // XCD-chunked swizzle: 1568 blocks, %8==0 -> bijective chunking.
  // XCD k owns 196 consecutive work items = 98 pixel tiles x both kout halves
  // = exactly 4 images per XCD: all halo/A reuse stays inside one L2.
  int bid = blockIdx.x;
  int swz = (bid & 7) * 196 + (bid >> 3);
  int m0 = (swz >> 1) * 128;         // pixel tile
  int n0 = (swz & 1) * 128;          // kout tile
  int wm = w >> 1, wn = w & 1;       // 2x2 wave grid, wave tile 64x64

  // staging assignment: wave w stages rows [32w,32w+32) of each tile
  int chunk = lane & 3;                         // 16B chunk within 64B row
  int r0 = (w << 5) + (lane >> 2);
  int r1 = r0 + 16;
  int cg0 = chunk ^ ((r0 >> 1) & 3);            // XOR swizzle on global side
  int cg1 = chunk ^ ((r1 >> 1) & 3);
  int p0 = m0 + r0, p1 = m0 + r1;
  int rem0 = p0 % 3136, rem1 = p1 % 3136;
  int y0 = rem0 / 56, x0 = rem0 % 56;
  int y1 = rem1 / 56, x1 = rem1 % 56;

  StagePtrs P;
  P.aBase0 = A4 + (size_t)p0 * 256 + cg0 * 16;
  P.aBase1 = A4 + (size_t)p1 * 256 + cg1 * 16;
  P.a8Base0 = P.aBase0 + ASZ;
  P.a8Base1 = P.aBase1 + ASZ;
  P.bBase0 = Wc + (n0 + r0) * 256 + cg0 * 16;
  P.bBase1 = Wc + (n0 + r1) * 256 + cg1 * 16;
  P.zp0 = zpage + chunk * 16;
  P.vm0 = 0; P.vm1 = 0;
#pragma unroll
  for (int win = 0; win < 9; ++win) {
    int dy = win / 3 - 1, dx = win % 3 - 1;
    P.vm0 |= (unsigned)(((unsigned)(y0 + dy) < 56u) & ((unsigned)(x0 + dx) < 56u)) << win;
    P.vm1 |= (unsigned)(((unsigned)(y1 + dy) < 56u) & ((unsigned)(x1 + dx) < 56u)) << win;
  }

  char* dA4 = &smA4[0][w << 11];
  char* dA8 = &smA8[0][w << 11];
  char* dB  = &smB[0][w << 11];
  const char* smA4f = &smA4[0][0];
  const char* smA8f = &smA8[0][0];
  const char* smBf  = &smB[0][0];

  v16i acc4[2][2] = {}, acc8[2][2] = {};
  int r31 = lane & 31, qh = lane >> 5;

  // precomputed per-lane LDS read offsets (swizzle folded in)
  int offA[2][2], offB[2][2];
#pragma unroll
  for (int fm = 0; fm < 2; ++fm) {
    int row = wm * 64 + fm * 32 + r31;
    int swl = (row >> 1) & 3;
#pragma unroll
    for (int kc = 0; kc < 2; ++kc)
      offA[fm][kc] = row * 64 + (((kc * 2 + qh) ^ swl) << 4);
  }
#pragma unroll
  for (int fn = 0; fn < 2; ++fn) {
    int row = wn * 64 + fn * 32 + r31;
    int swl = (row >> 1) & 3;
#pragma unroll
    for (int kc = 0; kc < 2; ++kc)
      offB[fn][kc] = row * 64 + (((kc * 2 + qh) ^ swl) << 4);
  }

  // ---- sub-phased schedule (T3+T4+T5): per K-stage, two sub-phases.
  // Each sub-phase: {6 ds_read_b128 for this kc  ||  issue half the stage-(s+2)
  // glds} -> s_barrier -> lgkmcnt(0) -> setprio(1) -> 8 MFMA -> setprio(0).
  // One wave's LDS-read burst overlaps other waves' MFMA clusters; the counted
  // vmcnt(6) at stage top keeps 6 glds (one full stage) in flight across phases.
#define SUBPHASE(S, RB, WB, KC)                                               \
  {                                                                           \
    v4i a4f[2], a8f[2], bf[2];                                                \
    _Pragma("unroll")                                                         \
    for (int fm = 0; fm < 2; ++fm) {                                          \
      a4f[fm] = *(const v4i*)(smA4f + (RB) * 8192 + offA[fm][KC]);            \
      a8f[fm] = *(const v4i*)(smA8f + (RB) * 8192 + offA[fm][KC]);            \
    }                                                                         \
    _Pragma("unroll")                                                         \
    for (int fn = 0; fn < 2; ++fn)                                            \
      bf[fn] = *(const v4i*)(smBf + (RB) * 8192 + offB[fn][KC]);              \
    issue_half((S) + 2, KC, P, dA4 + (WB) * 8192, dA8 + (WB) * 8192,          \
               dB + (WB) * 8192);                                             \
    asm volatile("s_barrier" ::: "memory");                                   \
    asm volatile("s_waitcnt lgkmcnt(0)" ::: "memory");                        \
    __builtin_amdgcn_s_setprio(1);                                            \
    _Pragma("unroll")                                                         \
    for (int fm = 0; fm < 2; ++fm)                                            \
      _Pragma("unroll")                                                       \
      for (int fn = 0; fn < 2; ++fn) {                                        \
        acc4[fm][fn] = __builtin_amdgcn_mfma_i32_32x32x32_i8(a4f[fm], bf[fn], acc4[fm][fn], 0, 0, 0); \
        acc8[fm][fn] = __builtin_amdgcn_mfma_i32_32x32x32_i8(a8f[fm], bf[fn], acc8[fm][fn], 0, 0, 0); \
      }                                                                       \
    __builtin_amdgcn_s_setprio(0);                                            \
  }

  // Stage top: retire stage S's 6 glds (oldest; S+1's 6 stay in flight), then
  // barrier so every wave's writes to RB are visible before any wave reads it.
#define PHASE(S, RB, WB)                                                      \
  {                                                                           \
    asm volatile("s_waitcnt vmcnt(6)" ::: "memory");                          \
    asm volatile("s_barrier" ::: "memory");                                   \
    SUBPHASE(S, RB, WB, 0)                                                    \
    SUBPHASE(S, RB, WB, 1)                                                    \
  }

  // prologue: stages 0 and 1 fully in flight (12 outstanding at first PHASE)
  issue_half(0, 0, P, dA4, dA8, dB);
  issue_half(0, 1, P, dA4, dA8, dB);
  issue_half(1, 0, P, dA4 + 8192, dA8 + 8192, dB + 8192);
  issue_half(1, 1, P, dA4 + 8192, dA8 + 8192, dB + 8192);

#pragma unroll 1
  for (int sp = 0; sp < 12; ++sp) {
    int s0 = sp * 3;
    PHASE(s0,     0, 2);     // compute buf0, prefetch s0+2 -> buf2
    PHASE(s0 + 1, 1, 0);     // compute buf1, prefetch s0+3 -> buf0
    PHASE(s0 + 2, 2, 1);     // compute buf2, prefetch s0+4 -> buf1
  }
  asm volatile("s_waitcnt vmcnt(0)" ::: "memory");     // retire dummy-stage LDS writes
#undef PHASE
#undef SUBPHASE

  // -------- epilogue: exact offset correction, scale, sigmoid gate, NCHW store --------
  float fs4 = q->s4sw, fs8 = q->s8sw;
  int dwv = q->dw;
#pragma unroll
  for (int fm = 0; fm < 2; ++fm)
#pragma unroll
    for (int fn = 0; fn < 2; ++fn) {
      int kout = n0 + wn * 64 + fn * 32 + r31;
      int pb = m0 + wm * 64 + fm * 32 + 4 * qh;
#pragma unroll
      for (int rg = 0; rg < 4; ++rg) {
        int pr = pb + 8 * rg;                   // 4 consecutive pixels, never cross image
        int4 sv4 = *(const int4*)(S4 + pr);
        int4 sv8 = *(const int4*)(S8 + pr);
        float4 res;
        res.x = pg_merge(acc4[fm][fn][rg * 4 + 0] + dwv * sv4.x,
                         acc8[fm][fn][rg * 4 + 0] + dwv * sv8.x, fs4, fs8);
        res.y = pg_merge(acc4[fm][fn][rg * 4 + 1] + dwv * sv4.y,
                         acc8[fm][fn][rg * 4 + 1] + dwv * sv8.y, fs4, fs8);
        res.z = pg_merge(acc4[fm][fn][rg * 4 + 2] + dwv * sv4.z,
                         acc8[fm][fn][rg * 4 + 2] + dwv * sv8.z, fs4, fs8);
        res.w = pg_merge(acc4[fm][fn][rg * 4 + 3] + dwv * sv4.w,
                         acc8[fm][fn][rg * 4 + 3] + dwv * sv8.w, fs4, fs8);
        int nimg = pr / 3136;
        int rem = pr - nimg * 3136;
        *(float4*)(out + (size_t)nimg * 802816 + (size_t)kout * 3136 + rem) = res;
      }
    }
}

// ---------------- launch: 4 kernels (was 8) ----------------
extern "C" void kernel_launch(void* const* d_in, const int* in_sizes, int n_in,
                              void* d_out, int out_size, void* d_ws, size_t ws_size,
                              hipStream_t stream) {
  const float* x  = (const float*)d_in[0];
  const float* wt = (const float*)d_in[1];
  float* out = (float*)d_out;

  char* ws = (char*)d_ws;
  float2* mmX = (float2*)ws;                    // 1024 float2 = 8192 B
  float2* mmW = (float2*)(ws + 8192);           // 64 float2 = 512 B
  QParams* prm = (QParams*)(ws + 8960);
  char* zpage = ws + 9728;                      // 512 B zeros (written by k_quant)
  char* A4 = ws + 10240;
  const size_t ASZ = 25690112;                  // 32*56*56*256
  char* A8 = A4 + ASZ;
  int* CS4 = (int*)(A8 + ASZ);
  int* CS8 = CS4 + 100352;
  int* S4  = CS8 + 100352;
  int* S8  = S4 + 100352;
  char* Wc = (char*)(S8 + 100352);              // 9*65536 bytes; total ~53.6 MB

  k_minmax2<<<1088, 256, 0, stream>>>((const float4*)x, 25690112 / 4,
                                      (const float4*)wt, 589824 / 4, mmX, mmW);
  k_quant<<<2048, 256, 0, stream>>>((const float4*)x, wt, mmX, mmW,
                                    A4, A8, CS4, CS8, Wc, prm, (unsigned*)zpage);
  k_wsum<<<392, 256, 0, stream>>>(CS4, CS8, S4, S8);
  k_conv<<<dim3(1568), 256, 0, stream>>>(A4, A8, Wc, S4, S8, prm, zpage, out);
}